// Round 1
// baseline (877.378 us; speedup 1.0000x reference)
//
#include <hip/hip_runtime.h>
#include <math.h>

typedef unsigned short u16;
typedef unsigned int   u32;
typedef short bf16x8 __attribute__((ext_vector_type(8)));
typedef float f32x4  __attribute__((ext_vector_type(4)));

// ---------- helpers ----------
__device__ __forceinline__ u16 f2bf(float f) {          // RNE fp32 -> bf16
  u32 u = __builtin_bit_cast(u32, f);
  u32 r = (u + 0x7fffu + ((u >> 16) & 1u)) >> 16;
  return (u16)r;
}
__device__ __forceinline__ float gelu_exact(float v) {
  return 0.5f * v * (1.0f + erff(v * 0.70710678118654752f));
}

// ws layout (bytes): [h bf16: 209715200][fw1: 53248][fw2: 50176]
#define H_BYTES   209715200ll
#define FW1_ELEMS 26624   // 4 kc * 13 nt * 64 lanes * 8
#define FW2_ELEMS 25088   // 7 kc * 7 nt * 64 lanes * 8

// ---------- weight fragment pre-swizzle ----------
// b_frag element j of lane, tile (kc,nt):  B[k = kc*32 + (lane>>4)*8 + j][n]
// conv1: k=c (pad 100->128), n=o (pad 200->208).  conv2: k=c (200->224), n=o (100->112).
__global__ void prep_frags(const float* __restrict__ w1, const float* __restrict__ w2,
                           u16* __restrict__ fw1, u16* __restrict__ fw2) {
  int gid = blockIdx.x * 256 + threadIdx.x;
  if (gid < FW1_ELEMS) {
    int j = gid & 7, lane = (gid >> 3) & 63, rest = gid >> 9;   // rest = kc*13+nt
    int nt = rest % 13, kc = rest / 13;
    int c = kc * 32 + (lane >> 4) * 8 + j;
    int o = nt * 16 + (lane & 15);
    float v = (c < 100 && o < 200) ? w1[o * 100 + c] : 0.f;
    fw1[gid] = f2bf(v);
  } else if (gid < FW1_ELEMS + FW2_ELEMS) {
    int i2 = gid - FW1_ELEMS;
    int j = i2 & 7, lane = (i2 >> 3) & 63, rest = i2 >> 9;      // rest = kc*7+nt
    int nt = rest % 7, kc = rest / 7;
    int c = kc * 32 + (lane >> 4) * 8 + j;
    int o = nt * 16 + (lane & 15);
    float v = (c < 200 && o < 100) ? w2[o * 200 + c] : 0.f;
    fw2[i2] = f2bf(v);
  }
}

// ---------- conv1: h = gelu(shift5(x) @ w1^T + b1), h stored bf16 ----------
#define SK1 136   // A-tile k-stride (128 + 8): keeps ds b128 ops at the 8-cycle balanced floor
__global__ __launch_bounds__(256, 3) void conv1_kernel(
    const float* __restrict__ x, const u16* __restrict__ fw1,
    const float* __restrict__ b1, u16* __restrict__ hbuf) {
  __shared__ __align__(16) u16 At[128 * SK1];   // 34816 B  A = xs^T tile [m=px][k=c]
  __shared__ __align__(16) u16 Ob[16 * 136];    //  4352 B  epilogue transpose buf [o][px]
  const int t  = threadIdx.x;
  const int bx = blockIdx.x;
  const int r  = bx >> 1;            // row id in [0, 8*256)
  const int b  = r >> 8;
  const int hh = r & 255;
  const int w0 = (bx & 1) << 7;      // half-row: 128 px

  // ---- stage shifted x -> bf16 LDS (each thread: 8 packs of 8 consecutive c) ----
  {
    const int m  = t & 127;
    const int kh = t >> 7;
    const int wp = w0 + m;
    #pragma unroll
    for (int g = 0; g < 8; ++g) {
      const int c0 = 8 * (kh + 2 * g);          // covers 0..127 in 8-blocks
      u32 pk[4];
      #pragma unroll
      for (int jj = 0; jj < 8; ++jj) {
        const int c = c0 + jj;
        float v = 0.f;
        if (c < 100) {                           // c>=100 is K-pad -> 0
          const int dw = (c < 20) ? 1 : ((c < 40) ? -1 : 0);
          const int dh = (c >= 40 && c < 60) ? 1 : ((c >= 60 && c < 80) ? -1 : 0);
          const int hs = hh + dh, ws = wp + dw;
          if ((unsigned)hs < 256u && (unsigned)ws < 256u)
            v = x[((b * 100 + c) * 256 + hs) * 256 + ws];
        }
        const u32 bv = f2bf(v);
        if (jj & 1) pk[jj >> 1] |= bv << 16; else pk[jj >> 1] = bv;
      }
      *(uint4*)&At[m * SK1 + c0] = make_uint4(pk[0], pk[1], pk[2], pk[3]);
    }
  }
  __syncthreads();

  // ---- K loop: D[px, o] += A[px, c] * B[c, o] ----
  const int lane = t & 63, wid = t >> 6;
  const int col = lane & 15, q = lane >> 4;
  f32x4 acc[2][13];
  #pragma unroll
  for (int i = 0; i < 2; ++i)
    #pragma unroll
    for (int nt = 0; nt < 13; ++nt) acc[i][nt] = (f32x4)0.0f;

  const bf16x8* wf = (const bf16x8*)fw1 + lane;
  #pragma unroll 1
  for (int kc = 0; kc < 4; ++kc) {
    const bf16x8 a0 = *(const bf16x8*)&At[((2 * wid + 0) * 16 + col) * SK1 + kc * 32 + q * 8];
    const bf16x8 a1 = *(const bf16x8*)&At[((2 * wid + 1) * 16 + col) * SK1 + kc * 32 + q * 8];
    #pragma unroll
    for (int nt = 0; nt < 13; ++nt) {
      const bf16x8 bf = wf[(kc * 13 + nt) * 64];
      acc[0][nt] = __builtin_amdgcn_mfma_f32_16x16x32_bf16(a0, bf, acc[0][nt], 0, 0, 0);
      acc[1][nt] = __builtin_amdgcn_mfma_f32_16x16x32_bf16(a1, bf, acc[1][nt], 0, 0, 0);
    }
  }

  // ---- epilogue: bias + gelu, LDS transpose, coalesced bf16 stores ----
  for (int nt = 0; nt < 13; ++nt) {
    __syncthreads();
    const int o = nt * 16 + col;
    const float bias = (o < 200) ? b1[o] : 0.f;
    #pragma unroll
    for (int i = 0; i < 2; ++i) {
      const f32x4 v = acc[i][nt];
      const u32 p0 = (u32)f2bf(gelu_exact(v[0] + bias)) | ((u32)f2bf(gelu_exact(v[1] + bias)) << 16);
      const u32 p1 = (u32)f2bf(gelu_exact(v[2] + bias)) | ((u32)f2bf(gelu_exact(v[3] + bias)) << 16);
      // D row = 4q + reg -> px = (2*wid+i)*16 + 4q + reg;  col -> o
      *(uint2*)&Ob[col * 136 + (2 * wid + i) * 16 + 4 * q] = make_uint2(p0, p1);
    }
    __syncthreads();
    const int oo = nt * 16 + (t >> 4);
    if (oo < 200) {
      const int idx = t & 15;
      const uint4 d = *(const uint4*)&Ob[(t >> 4) * 136 + 8 * idx];
      *(uint4*)&hbuf[((b * 200 + oo) * 256 + hh) * 256 + w0 + 8 * idx] = d;
    }
  }
}

// ---------- conv2: out = shift5(h) @ w2^T + b2 (fp32 out) ----------
#define SK2 232   // 224 + 8
__global__ __launch_bounds__(256, 2) void conv2_kernel(
    const u16* __restrict__ hbuf, const u16* __restrict__ fw2,
    const float* __restrict__ b2, float* __restrict__ out) {
  __shared__ __align__(16) char smem[128 * SK2 * 2];   // 59392 B; A-tile, reused as fp32 Ob
  u16*   At = (u16*)smem;
  float* Ob = (float*)smem;                            // 16*136*4 = 8704 B (A dead by then)
  const int t  = threadIdx.x;
  const int bx = blockIdx.x;
  const int r  = bx >> 1;
  const int b  = r >> 8;
  const int hh = r & 255;
  const int w0 = (bx & 1) << 7;

  // ---- stage shifted h (already bf16; 14 packs of 8 c per thread) ----
  {
    const int m  = t & 127;
    const int kh = t >> 7;
    const int wp = w0 + m;
    #pragma unroll
    for (int g = 0; g < 14; ++g) {
      const int c0 = 8 * (kh + 2 * g);          // covers 0..223
      u32 pk[4];
      #pragma unroll
      for (int jj = 0; jj < 8; ++jj) {
        const int c = c0 + jj;
        u32 bv = 0;
        if (c < 200) {
          const int dw = (c < 40) ? 1 : ((c < 80) ? -1 : 0);
          const int dh = (c >= 80 && c < 120) ? 1 : ((c >= 120 && c < 160) ? -1 : 0);
          const int hs = hh + dh, ws = wp + dw;
          if ((unsigned)hs < 256u && (unsigned)ws < 256u)
            bv = hbuf[((b * 200 + c) * 256 + hs) * 256 + ws];
        }
        if (jj & 1) pk[jj >> 1] |= bv << 16; else pk[jj >> 1] = bv;
      }
      *(uint4*)&At[m * SK2 + c0] = make_uint4(pk[0], pk[1], pk[2], pk[3]);
    }
  }
  __syncthreads();

  const int lane = t & 63, wid = t >> 6;
  const int col = lane & 15, q = lane >> 4;
  f32x4 acc[2][7];
  #pragma unroll
  for (int i = 0; i < 2; ++i)
    #pragma unroll
    for (int nt = 0; nt < 7; ++nt) acc[i][nt] = (f32x4)0.0f;

  const bf16x8* wf = (const bf16x8*)fw2 + lane;
  #pragma unroll 1
  for (int kc = 0; kc < 7; ++kc) {
    const bf16x8 a0 = *(const bf16x8*)&At[((2 * wid + 0) * 16 + col) * SK2 + kc * 32 + q * 8];
    const bf16x8 a1 = *(const bf16x8*)&At[((2 * wid + 1) * 16 + col) * SK2 + kc * 32 + q * 8];
    #pragma unroll
    for (int nt = 0; nt < 7; ++nt) {
      const bf16x8 bf = wf[(kc * 7 + nt) * 64];
      acc[0][nt] = __builtin_amdgcn_mfma_f32_16x16x32_bf16(a0, bf, acc[0][nt], 0, 0, 0);
      acc[1][nt] = __builtin_amdgcn_mfma_f32_16x16x32_bf16(a1, bf, acc[1][nt], 0, 0, 0);
    }
  }

  // ---- epilogue: + b2, LDS transpose, coalesced fp32 stores ----
  for (int nt = 0; nt < 7; ++nt) {
    __syncthreads();   // first iter also guarantees all waves finished reading At
    const int o = nt * 16 + col;
    const float bias = (o < 100) ? b2[o] : 0.f;
    #pragma unroll
    for (int i = 0; i < 2; ++i) {
      const f32x4 v = acc[i][nt];
      *(float4*)&Ob[col * 136 + (2 * wid + i) * 16 + 4 * q] =
          make_float4(v[0] + bias, v[1] + bias, v[2] + bias, v[3] + bias);
    }
    __syncthreads();
    const int oo = nt * 16 + (t >> 4);
    if (oo < 100) {
      const int idx = t & 15;
      const int base = ((b * 100 + oo) * 256 + hh) * 256 + w0 + 8 * idx;
      const float4 d0 = *(const float4*)&Ob[(t >> 4) * 136 + 8 * idx];
      const float4 d1 = *(const float4*)&Ob[(t >> 4) * 136 + 8 * idx + 4];
      *(float4*)&out[base]     = d0;
      *(float4*)&out[base + 4] = d1;
    }
  }
}

extern "C" void kernel_launch(void* const* d_in, const int* in_sizes, int n_in,
                              void* d_out, int out_size, void* d_ws, size_t ws_size,
                              hipStream_t stream) {
  const float* x  = (const float*)d_in[0];
  const float* w1 = (const float*)d_in[1];
  const float* b1 = (const float*)d_in[2];
  const float* w2 = (const float*)d_in[3];
  const float* b2 = (const float*)d_in[4];
  float* out = (float*)d_out;

  u16* hbuf = (u16*)d_ws;
  u16* fw1  = (u16*)((char*)d_ws + H_BYTES);
  u16* fw2  = (u16*)((char*)d_ws + H_BYTES + FW1_ELEMS * 2);

  prep_frags<<<202, 256, 0, stream>>>(w1, w2, fw1, fw2);
  conv1_kernel<<<4096, 256, 0, stream>>>(x, fw1, b1, hbuf);
  conv2_kernel<<<4096, 256, 0, stream>>>(hbuf, fw2, b2, out);
}